// Round 3
// baseline (2011.475 us; speedup 1.0000x reference)
//
#include <hip/hip_runtime.h>
#include <hip/hip_bf16.h>
#include <stdint.h>

typedef __hip_bfloat16 bf16;
typedef __attribute__((ext_vector_type(8))) short short8;
typedef __attribute__((ext_vector_type(4))) float f32x4;

#define INFV 1e12f

constexpr int Vv = 45000;
constexpr int VE = 45010;

static __device__ __forceinline__ float bf2f(unsigned short u){
  union{ unsigned int i; float f; } w; w.i = ((unsigned int)u) << 16; return w.f;
}
static __device__ __forceinline__ unsigned short f2bf(float x){
  union { __hip_bfloat16 h; unsigned short u; } w; w.h = __float2bfloat16(x); return w.u;
}

// ---------------------------------------------------------------------------
// Generic bf16 MFMA GEMM: C[M,N] = A[M,K] @ B^T (B stored [N][K]) + bias
// mode 0: f32 out; 1: bf16 out; 2: bf16 tanh out. Cols [N,NZ) written 0.
// ---------------------------------------------------------------------------
__launch_bounds__(256, 2)
__global__ void k_mm(const unsigned short* __restrict__ A, int lda,
                     const unsigned short* __restrict__ B, int ldb, int NB,
                     const float* __restrict__ bias,
                     void* __restrict__ C, int ldc,
                     int M, int N, int NZ, int K, int mode)
{
  __shared__ char smem[20480];
  char* smA = smem;          // 128 rows x 64B, pitch 80
  char* smB = smem + 10240;
  int tid = threadIdx.x, lane = tid & 63;
  int w = tid >> 6, wr = w >> 1, wc = w & 1;
  int m0 = blockIdx.y * 128, n0 = blockIdx.x * 128;
  int l15 = lane & 15, lh = lane >> 4;
  f32x4 zero = {0.f,0.f,0.f,0.f};
  f32x4 acc[4][4];
  #pragma unroll
  for (int mi = 0; mi < 4; ++mi)
    #pragma unroll
    for (int ni = 0; ni < 4; ++ni) acc[mi][ni] = zero;
  short8 z8 = {0,0,0,0,0,0,0,0};

  for (int kc = 0; kc < K; kc += 32){
    #pragma unroll
    for (int call = 0; call < 2; ++call){
      int o = call*4096 + tid*16;
      int r = o >> 6, cb = o & 63;
      short8 va = z8, vb = z8;
      if (m0 + r < M)  va = *(const short8*)((const char*)A + ((size_t)(m0+r)*lda + kc)*2 + cb);
      if (n0 + r < NB) vb = *(const short8*)((const char*)B + ((size_t)(n0+r)*ldb + kc)*2 + cb);
      *(short8*)(smA + r*80 + cb) = va;
      *(short8*)(smB + r*80 + cb) = vb;
    }
    __syncthreads();
    short8 af[4], bfv[4];
    #pragma unroll
    for (int mi = 0; mi < 4; ++mi) af[mi]  = *(const short8*)(smA + (wr*64 + mi*16 + l15)*80 + lh*16);
    #pragma unroll
    for (int ni = 0; ni < 4; ++ni) bfv[ni] = *(const short8*)(smB + (wc*64 + ni*16 + l15)*80 + lh*16);
    #pragma unroll
    for (int mi = 0; mi < 4; ++mi)
      #pragma unroll
      for (int ni = 0; ni < 4; ++ni)
        acc[mi][ni] = __builtin_amdgcn_mfma_f32_16x16x32_bf16(af[mi], bfv[ni], acc[mi][ni], 0, 0, 0);
    __syncthreads();
  }

  #pragma unroll
  for (int mi = 0; mi < 4; ++mi){
    #pragma unroll
    for (int ni = 0; ni < 4; ++ni){
      #pragma unroll
      for (int j = 0; j < 4; ++j){
        int gr = m0 + wr*64 + mi*16 + 4*lh + j;
        int cg = n0 + wc*64 + ni*16 + l15;
        if (gr < M && cg < NZ){
          float v = (cg < N) ? acc[mi][ni][j] + (bias ? bias[cg] : 0.f) : 0.f;
          if (mode == 0) ((float*)C)[(size_t)gr*ldc + cg] = v;
          else {
            if (mode == 2) v = tanhf(v);
            ((unsigned short*)C)[(size_t)gr*ldc + cg] = f2bf(v);
          }
        }
      }
    }
  }
}

// ---------------------------------------------------------------------------
// merged transposes: f32 [K][N] -> bf16 [N2][K2] zero-padded, 5 regions
// ---------------------------------------------------------------------------
static __device__ __forceinline__ void tile64t(const float* __restrict__ in, int ldin,
                                               unsigned short* __restrict__ out,
                                               int K, int N, int K2, int N2,
                                               int bx, int by, int tid)
{
  __shared__ float tl[64][65];
  int n0 = bx * 64, k0 = by * 64;
  for (int idx = tid; idx < 64*64; idx += 256){
    int r = idx >> 6, c = idx & 63;
    int gk = k0 + r, gn = n0 + c;
    tl[r][c] = (gk < K && gn < N) ? in[(size_t)gk*ldin + gn] : 0.f;
  }
  __syncthreads();
  for (int idx = tid; idx < 64*64; idx += 256){
    int r = idx >> 6, c = idx & 63;
    int gn = n0 + r, gk = k0 + c;
    if (gn < N2 && gk < K2) out[(size_t)gn*K2 + gk] = f2bf(tl[c][r]);
  }
}

__launch_bounds__(256)
__global__ void k_trans(const float* __restrict__ W_out, unsigned short* __restrict__ WoT,
                        const float* __restrict__ W_enc, unsigned short* __restrict__ WencT,
                        const float* __restrict__ W_ih,  unsigned short* __restrict__ WihT,
                        const float* __restrict__ W_red, unsigned short* __restrict__ WredT1,
                        const float* __restrict__ W_cat, unsigned short* __restrict__ WcatT)
{
  int blk = blockIdx.x, tid = threadIdx.x;
  if (blk < 5632)      tile64t(W_out, 45000, WoT,   512, 45000, 512, 45056, blk % 704,        blk / 704,        tid);
  else if (blk < 5760) tile64t(W_enc, 512,   WencT, 1024, 512, 1024, 512,  (blk-5632) % 8,   (blk-5632) / 8,   tid);
  else if (blk < 5920) tile64t(W_ih,  2048,  WihT,  300, 2048,  320, 2048, (blk-5760) % 32,  (blk-5760) / 32,  tid);
  else if (blk < 5945) tile64t(W_red, 300,   WredT1,300, 300,   320, 320,  (blk-5920) % 5,   (blk-5920) / 5,   tid);
  else                 tile64t(W_cat, 512,   WcatT, 1024, 512, 1024, 512,  (blk-5945) % 8,   (blk-5945) / 8,   tid);
}

// ---------------------------------------------------------------------------
// merged converts: Acat bf16 concat, EmbAb gather (pad 320), Wred2b (pad 320)
// ---------------------------------------------------------------------------
__global__ void k_prep(const float* __restrict__ tree, const float* __restrict__ enc,
                       unsigned short* __restrict__ Acat,
                       const int* __restrict__ trg, const float* __restrict__ emb,
                       unsigned short* __restrict__ EmbAb,
                       const float* __restrict__ Wred2, unsigned short* __restrict__ Wred2b)
{
  int i = blockIdx.x*256 + threadIdx.x;
  const int nA = 3200*1024, nB = 1024*320, nC = 512*320;
  if (i < nA){
    int r = i >> 10, c = i & 1023;
    float v = (c < 512) ? tree[(size_t)r*512 + c] : enc[(size_t)r*512 + (c - 512)];
    Acat[i] = f2bf(v);
  } else if (i < nA + nB){
    int i2 = i - nA;
    int r = i2 / 320, c = i2 - r*320;
    EmbAb[i2] = (c < 300) ? f2bf(emb[(size_t)trg[r]*300 + c]) : (unsigned short)0;
  } else if (i < nA + nB + nC){
    int i3 = i - nA - nB;
    int r = i3 / 320, c = i3 - r*320;
    Wred2b[i3] = (c < 300) ? f2bf(Wred2[(size_t)r*300 + c]) : (unsigned short)0;
  }
}

// ---------------------------------------------------------------------------
// device-wide sense barrier (64 co-resident blocks, agent-scope atomics)
// ---------------------------------------------------------------------------
static __device__ __forceinline__ void gbar(int* cnt, int* gen, int nblk){
  __syncthreads();
  if (threadIdx.x == 0){
    __threadfence();
    int g = __hip_atomic_load(gen, __ATOMIC_RELAXED, __HIP_MEMORY_SCOPE_AGENT);
    int prev = __hip_atomic_fetch_add(cnt, 1, __ATOMIC_ACQ_REL, __HIP_MEMORY_SCOPE_AGENT);
    if (prev == nblk - 1){
      __hip_atomic_store(cnt, 0, __ATOMIC_RELAXED, __HIP_MEMORY_SCOPE_AGENT);
      __hip_atomic_store(gen, g + 1, __ATOMIC_RELEASE, __HIP_MEMORY_SCOPE_AGENT);
    } else {
      while (__hip_atomic_load(gen, __ATOMIC_ACQUIRE, __HIP_MEMORY_SCOPE_AGENT) == g)
        __builtin_amdgcn_s_sleep(2);
    }
    __threadfence();
  }
  __syncthreads();
}

// ---------------------------------------------------------------------------
// persistent recurrence: 64 blocks. blk<32: gates (LDS-resident weight slice,
// LSTM c-state in registers). blk>=32: attention (LDS-resident memories).
// ---------------------------------------------------------------------------
__launch_bounds__(256, 1)
__global__ void k_rec(const float* __restrict__ Wf, const float* __restrict__ W_hh,
                      const float* __restrict__ G1,
                      const float* __restrict__ b_ih, const float* __restrict__ b_hh,
                      const float* __restrict__ h0, const float* __restrict__ c0,
                      const unsigned short* __restrict__ memB,
                      const unsigned char* __restrict__ emask,
                      unsigned short* __restrict__ HCa, unsigned short* __restrict__ HCb,
                      unsigned short* __restrict__ HCz, float* __restrict__ Esave,
                      int* __restrict__ bar)
{
  __shared__ char lds[131072];
  int tid = threadIdx.x, lane = tid & 63, blk = blockIdx.x;
  int* cnt = bar; int* gen = bar + 16;

  if (blk < 32){
    // ================= gate role =================
    int w2 = tid >> 6, l15 = lane & 15, lh = lane >> 4;
    // stage 64-col weight slice [c_local][k], XOR-swizzled, bf16 (128 KB)
    for (int it = 0; it < 256; ++it){
      int grp = it*16 + (tid >> 4);          // (k,q) group
      int k = grp >> 2, q = grp & 3, i = tid & 15;
      int cl = 4*i + q;
      float v = (k < 512) ? Wf  [(size_t)k      *2048 + q*512 + blk*16 + i]
                          : W_hh[(size_t)(k-512)*2048 + q*512 + blk*16 + i];
      *(unsigned short*)(lds + cl*2048 + ((k*2) ^ ((cl & 7) << 4))) = f2bf(v);
    }
    int cg = blk*64 + w2*16 + l15;
    int hfull = cg >> 2, q = cg & 3;
    float bsumv = b_ih[q*512 + hfull] + b_hh[q*512 + hfull];
    float creg[2][4];
    #pragma unroll
    for (int f = 0; f < 2; ++f)
      #pragma unroll
      for (int j = 0; j < 4; ++j)
        creg[f][j] = c0[(f*16 + 4*lh + j)*512 + hfull];

    gbar(cnt, gen, 64);

    for (int t = 0; t < 32; ++t){
      const char* Ab = (const char*)((t & 1) ? HCb : HCa);
      unsigned short* HCn = (t & 1) ? HCa : HCb;
      f32x4 zero = {0.f,0.f,0.f,0.f};
      f32x4 acc0 = zero, acc1 = zero;
      int cl = w2*16 + l15;
      int xm = (cl & 7) << 4;
      #pragma unroll 8
      for (int kc = 0; kc < 1024; kc += 32){
        short8 a0 = *(const short8*)(Ab + l15*2048      + kc*2 + lh*16);
        short8 a1 = *(const short8*)(Ab + (l15+16)*2048 + kc*2 + lh*16);
        short8 bfr = *(const short8*)(lds + cl*2048 + ((kc*2 + lh*16) ^ xm));
        acc0 = __builtin_amdgcn_mfma_f32_16x16x32_bf16(a0, bfr, acc0, 0, 0, 0);
        acc1 = __builtin_amdgcn_mfma_f32_16x16x32_bf16(a1, bfr, acc1, 0, 0, 0);
      }
      #pragma unroll
      for (int f = 0; f < 2; ++f){
        #pragma unroll
        for (int j = 0; j < 4; ++j){
          int brow = f*16 + 4*lh + j;
          float g = (f ? acc1[j] : acc0[j])
                  + G1[((size_t)brow*32 + t)*2048 + q*512 + hfull] + bsumv;
          float x1 = (q == 2) ? tanhf(g) : 1.f/(1.f + expf(-g));
          float xg = __shfl_xor(x1, 2);
          float xf = __shfl_xor(x1, 1);
          float xo = __shfl_xor(x1, 3);
          if (q == 0){
            float cn = xf*creg[f][j] + x1*xg;
            creg[f][j] = cn;
            float hn = xo * tanhf(cn);
            unsigned short hb = f2bf(hn);
            HCn[brow*1024 + 512 + hfull] = hb;
            HCz[((size_t)brow*32 + t)*1024 + hfull] = hb;
          }
        }
      }
      gbar(cnt, gen, 64);   // h published
      gbar(cnt, gen, 64);   // ctx published (by attn blocks)
    }
  } else {
    // ================= attention role =================
    int b = blk - 32;
    float* E_s   = (float*)(lds + 102400);
    float* att_s = (float*)(lds + 102816);
    // stage memories row-block [100][512] bf16 (100 KB)
    for (int idx = tid; idx < 6400; idx += 256)
      *(short8*)(lds + idx*16) = *(const short8*)((const char*)memB + (size_t)b*102400 + idx*16);
    // initial state HC0 = (ctx=0 | h0)
    for (int i = tid; i < 1024; i += 256)
      HCa[b*1024 + i] = (i < 512) ? (unsigned short)0 : f2bf(h0[b*512 + i - 512]);

    gbar(cnt, gen, 64);

    int w = tid >> 6;
    for (int t = 0; t < 32; ++t){
      gbar(cnt, gen, 64);   // wait for h
      unsigned short* HCn = (t & 1) ? HCa : HCb;
      float hreg[8];
      {
        short8 hv = *(const short8*)(HCn + b*1024 + 512 + lane*8);
        #pragma unroll
        for (int i = 0; i < 8; ++i) hreg[i] = bf2f((unsigned short)hv[i]);
      }
      for (int s = w; s < 100; s += 4){
        short8 mv = *(const short8*)(lds + s*1024 + lane*16);
        float a = 0.f;
        #pragma unroll
        for (int i = 0; i < 8; ++i) a = fmaf(hreg[i], bf2f((unsigned short)mv[i]), a);
        #pragma unroll
        for (int d = 1; d < 64; d <<= 1) a += __shfl_xor(a, d);
        if (lane == 0){
          float e = emask[b*100 + s] ? -INFV : a;
          E_s[s] = e;
          Esave[((size_t)b*32 + t)*100 + s] = e;
        }
      }
      __syncthreads();
      if (w == 0){
        float ea = (lane < 100) ? E_s[lane] : -INFV;
        float eb = (lane + 64 < 100) ? E_s[lane + 64] : -INFV;
        float m = fmaxf(ea, eb);
        #pragma unroll
        for (int d = 1; d < 64; d <<= 1) m = fmaxf(m, __shfl_xor(m, d));
        float p = ((lane < 100) ? expf(ea - m) : 0.f) + ((lane + 64 < 100) ? expf(eb - m) : 0.f);
        #pragma unroll
        for (int d = 1; d < 64; d <<= 1) p += __shfl_xor(p, d);
        float inv = 1.f / p;
        if (lane < 100)      att_s[lane]      = expf(ea - m) * inv;
        if (lane + 64 < 100) att_s[lane + 64] = expf(eb - m) * inv;
      }
      __syncthreads();
      for (int hh = tid; hh < 512; hh += 256){
        float a = 0.f;
        for (int s = 0; s < 100; ++s)
          a = fmaf(att_s[s], bf2f(*(const unsigned short*)(lds + s*1024 + hh*2)), a);
        unsigned short cbv = f2bf(a);
        HCn[b*1024 + hh] = cbv;
        HCz[((size_t)b*32 + t)*1024 + 512 + hh] = cbv;
      }
      gbar(cnt, gen, 64);   // ctx published
    }
  }
}

// ---------------------------------------------------------------------------
// final: logits = Z @ WoT^T + b_out, fused scatter-max + INF rules
// 64 KB LDS (full 128x128 smax), 2 blocks/CU, reg-staged k-pipeline
// ---------------------------------------------------------------------------
__launch_bounds__(256, 2)
__global__ void k_logits(const unsigned short* __restrict__ Zbf,
                         const unsigned short* __restrict__ WoT,
                         const float* __restrict__ b_out,
                         const float* __restrict__ Esave,
                         const int* __restrict__ ext_src,
                         float* __restrict__ out)
{
  __shared__ char smem[65536];
  char* smA = smem;                  // 128 rows x 64B, pitch 80
  char* smB = smem + 10240;
  int tid = threadIdx.x, lane = tid & 63;
  int w = tid >> 6, wr = w >> 1, wc = w & 1;
  int m0 = blockIdx.y * 128, n0 = blockIdx.x * 128;
  int l15 = lane & 15, lh = lane >> 4;
  f32x4 zero = {0.f,0.f,0.f,0.f};
  f32x4 acc[4][4];
  #pragma unroll
  for (int mi = 0; mi < 4; ++mi)
    #pragma unroll
    for (int ni = 0; ni < 4; ++ni) acc[mi][ni] = zero;

  short8 va[2], vb[2];
  #pragma unroll
  for (int call = 0; call < 2; ++call){
    int o = call*4096 + tid*16; int r = o >> 6, cb = o & 63;
    va[call] = *(const short8*)((const char*)Zbf + (size_t)(m0 + r)*1024 + cb);
    vb[call] = *(const short8*)((const char*)WoT + (size_t)(n0 + r)*1024 + cb);
  }
  for (int kc = 0; kc < 512; kc += 32){
    #pragma unroll
    for (int call = 0; call < 2; ++call){
      int o = call*4096 + tid*16; int r = o >> 6, cb = o & 63;
      *(short8*)(smA + r*80 + cb) = va[call];
      *(short8*)(smB + r*80 + cb) = vb[call];
    }
    __syncthreads();
    if (kc < 480){
      #pragma unroll
      for (int call = 0; call < 2; ++call){
        int o = call*4096 + tid*16; int r = o >> 6, cb = o & 63;
        va[call] = *(const short8*)((const char*)Zbf + (size_t)(m0 + r)*1024 + (kc+32)*2 + cb);
        vb[call] = *(const short8*)((const char*)WoT + (size_t)(n0 + r)*1024 + (kc+32)*2 + cb);
      }
    }
    short8 af[4], bfv[4];
    #pragma unroll
    for (int mi = 0; mi < 4; ++mi) af[mi]  = *(const short8*)(smA + (wr*64 + mi*16 + l15)*80 + lh*16);
    #pragma unroll
    for (int ni = 0; ni < 4; ++ni) bfv[ni] = *(const short8*)(smB + (wc*64 + ni*16 + l15)*80 + lh*16);
    #pragma unroll
    for (int mi = 0; mi < 4; ++mi)
      #pragma unroll
      for (int ni = 0; ni < 4; ++ni)
        acc[mi][ni] = __builtin_amdgcn_mfma_f32_16x16x32_bf16(af[mi], bfv[ni], acc[mi][ni], 0, 0, 0);
    __syncthreads();
  }

  // scatter-max table over this tile's 128 cols, per row (64 KB)
  float* smax = (float*)smem;
  for (int i = tid; i < 128*128; i += 256) smax[i] = -INFV;
  __syncthreads();
  if (tid < 128){
    int rg = m0 + tid;
    int b = rg >> 5;
    const int* es = ext_src + b*100;
    const float* ev = Esave + (size_t)rg*100;
    float* row = smax + tid*128;
    for (int s = 0; s < 100; ++s){
      unsigned int d = (unsigned int)(es[s] - n0);
      if (d < 128u){
        float e = ev[s];
        if (e > -9e11f && e > row[d]) row[d] = e;
      }
    }
  }
  __syncthreads();

  #pragma unroll
  for (int mi = 0; mi < 4; ++mi){
    #pragma unroll
    for (int ni = 0; ni < 4; ++ni){
      #pragma unroll
      for (int j = 0; j < 4; ++j){
        int rl = wr*64 + mi*16 + 4*lh + j;
        int cl = wc*64 + ni*16 + l15;
        int cg = n0 + cl;
        if (cg < VE){
          float v = acc[mi][ni][j];
          float base = (cg < Vv) ? (v + b_out[cg]) : 0.f;
          float sm = smax[rl*128 + cl];
          float o = base + (sm > -9e11f ? sm : 0.f);
          if (o == 0.f) o = -INFV;
          out[(size_t)(m0 + rl)*VE + cg] = o;
        }
      }
    }
  }
}

// ---------------------------------------------------------------------------
extern "C" void kernel_launch(void* const* d_in, const int* in_sizes, int n_in,
                              void* d_out, int out_size, void* d_ws, size_t ws_size,
                              hipStream_t stream)
{
  const int*   trg    = (const int*)  d_in[0];
  const int*   ext    = (const int*)  d_in[1];
  const float* h0     = (const float*)d_in[2];
  const float* c0     = (const float*)d_in[3];
  const float* tree   = (const float*)d_in[4];
  const float* enc    = (const float*)d_in[6];
  const unsigned char* emask = (const unsigned char*)d_in[7];
  const float* emb    = (const float*)d_in[8];
  const float* W_enc  = (const float*)d_in[9];
  const float* b_enc  = (const float*)d_in[10];
  const float* W_red  = (const float*)d_in[11];
  const float* b_red  = (const float*)d_in[12];
  const float* W_ih   = (const float*)d_in[13];
  const float* W_hh   = (const float*)d_in[14];
  const float* b_ih   = (const float*)d_in[15];
  const float* b_hh   = (const float*)d_in[16];
  const float* W_cat  = (const float*)d_in[17];
  const float* b_cat  = (const float*)d_in[18];
  const float* W_out  = (const float*)d_in[19];
  const float* b_out  = (const float*)d_in[20];
  float* out = (float*)d_out;

  char* ws = (char*)d_ws;
  size_t off = 0;
  auto alloc = [&](size_t bytes)->char*{
    char* p = ws + off; off = (off + bytes + 255) & ~(size_t)255; return p;
  };
  unsigned short* Acat  = (unsigned short*)alloc(3200ull*1024*2);
  unsigned short* WencT = (unsigned short*)alloc(512ull*1024*2);
  unsigned short* memB  = (unsigned short*)alloc(3200ull*512*2);
  unsigned short* EmbAb = (unsigned short*)alloc(1024ull*320*2);
  unsigned short* WredT1= (unsigned short*)alloc(320ull*320*2);
  unsigned short* X0b   = (unsigned short*)alloc(1024ull*320*2);   // rows 0..1023
  unsigned short* Wred2b= (unsigned short*)alloc(512ull*320*2);    // rows 1024..1535 (contiguous)
  unsigned short* WihT  = (unsigned short*)alloc(2048ull*320*2);
  float*          G1    = (float*)         alloc(1024ull*2048*4);  // rows 0..1023
  float*          Wfbuf = (float*)         alloc(512ull*2048*4);   // rows 1024..1535 (contiguous)
  unsigned short* WoT   = (unsigned short*)alloc(45056ull*512*2);
  unsigned short* WcatT = (unsigned short*)alloc(512ull*1024*2);
  unsigned short* HCa   = (unsigned short*)alloc(32*1024*2);
  unsigned short* HCb   = (unsigned short*)alloc(32*1024*2);
  unsigned short* HCz   = (unsigned short*)alloc(1024ull*1024*2);
  unsigned short* Zbf   = (unsigned short*)alloc(1024ull*512*2);
  float*          Esave = (float*)         alloc(1024ull*100*4);
  int*            bar   = (int*)           alloc(256);
  (void)Wred2b; (void)Wfbuf;

  hipMemsetAsync(bar, 0, 128, stream);

  // all weight transposes (incl. WoT) in one launch
  k_trans<<<6073, 256, 0, stream>>>(W_out, WoT, W_enc, WencT, W_ih, WihT,
                                    W_red, WredT1, W_cat, WcatT);
  // all converts/gathers in one launch
  k_prep<<<14720, 256, 0, stream>>>(tree, enc, Acat, trg, emb, EmbAb,
                                    W_red + 300*300, Wred2b);

  // memories -> memB bf16 [3200][512]
  k_mm<<<dim3(4,25), 256, 0, stream>>>(Acat, 1024, WencT, 1024, 512, b_enc,
                                       memB, 512, 3200, 512, 512, 1024, 1);
  // X0b = (emb@W_red1 + b_red) bf16 [1024][320]
  k_mm<<<dim3(3,8), 256, 0, stream>>>(EmbAb, 320, WredT1, 320, 320, b_red,
                                      X0b, 320, 1024, 300, 320, 320, 1);
  // [G1 ; Wf] = [X0b ; Wred2b] @ W_ih   (f32, [1536][2048]); bsum folded into k_rec
  k_mm<<<dim3(16,12), 256, 0, stream>>>(X0b, 320, WihT, 320, 2048, nullptr,
                                        G1, 2048, 1536, 2048, 2048, 320, 0);

  // persistent recurrence (replaces 64 launches)
  k_rec<<<64, 256, 0, stream>>>(G1 + 1024ull*2048, W_hh, G1, b_ih, b_hh, h0, c0,
                                memB, emask, HCa, HCb, HCz, Esave, bar);

  // Z = tanh([h|ctx] @ W_cat + b_cat) -> bf16
  k_mm<<<dim3(4,8), 256, 0, stream>>>(HCz, 1024, WcatT, 1024, 512, b_cat,
                                      Zbf, 512, 1024, 512, 512, 1024, 2);
  // logits + pointer scatter + INF rules
  k_logits<<<dim3(352,8), 256, 0, stream>>>(Zbf, WoT, b_out, Esave, ext, out);
}